// Round 2
// baseline (977.575 us; speedup 1.0000x reference)
//
#include <hip/hip_runtime.h>
#include <vector>
#include <cstdint>
#include <cstddef>

// ---------------------------------------------------------------------------
// EncoderVidCRN on MI355X. Global tensors f32; MFMA in f16 (verified R2:
// absmax 2e-3 vs 9.9e-3 threshold). R3: weights pre-converted to f16 so the
// GEMM W-side (and f16 A-sides) stage via global_load_lds (m97 path).
// R5 (this round): f32 A-side goes back to register-staged convert (f16 in
// LDS, zero-conflict layout) -- R4's f32-in-LDS had an unfixable 8-way bank
// conflict (row stride 128B = full bank sweep) AND doubled A ds_read traffic,
// which was the measured binder (MfmaUtil 13.5% == LDS-throughput model).
// K-loop restructured to the m248 single-barrier bottom-drain recipe:
//   issue stage(t+1) -> compute(t) -> [commit A(t+1) to other buf] -> sync
// Loads overlap compute; ONE barrier per K-step; LDS 32KB/block.
// ---------------------------------------------------------------------------

typedef unsigned short u16;
typedef unsigned int u32;

typedef _Float16 h16;
typedef h16  h8 __attribute__((ext_vector_type(8)));
typedef h16  h4 __attribute__((ext_vector_type(4)));
typedef float f4 __attribute__((ext_vector_type(4)));
typedef float f32x4 __attribute__((ext_vector_type(4)));

enum { EPI_NONE=0, EPI_ELU=1, EPI_GATE=2 };

__device__ __forceinline__ h8 ld16f_as_h8(const float* p){
  f4 x0 = *(const f4*)p, x1 = *(const f4*)(p+4);
  h4 a = __builtin_convertvector(x0, h4);
  h4 b = __builtin_convertvector(x1, h4);
  return __builtin_shufflevector(a, b, 0,1,2,3,4,5,6,7);
}

// f16 direct-to-LDS path (m97). LDS dest = wave-uniform base + lane*16B:
// lane L of chunk c lands at elem c*512 + L*8 = row(c*16+(L>>2))*32 + (L&3)*8,
// i.e. slot L&3; so lane loads global granule kq = (L&3) ^ s(row) so that
// the fragment-read swizzle (slot = quad ^ s(row)) recovers it.
__device__ __forceinline__ void stage_async(const h16* base, long ld, int k0,
                                            h16* lds, int wave, int lane){
#pragma unroll
  for(int cc=0;cc<2;cc++){
    const int c = wave*2+cc;
    const int r = c*16 + (lane>>2);
    const int kq = (lane&3) ^ ((r>>1)&3);
    const h16* g = base + (long)r*ld + k0 + kq*8;
    __builtin_amdgcn_global_load_lds(
        (const __attribute__((address_space(1))) void*)g,
        (__attribute__((address_space(3))) void*)&lds[c*512], 16, 0, 0);
  }
}

// f32 register-staged path (R3-proven zero-conflict layout): thread t ->
// row r = t>>1, k-half (t&1)*16. Granule kq of row r stored at slot
// kq ^ ((r>>1)&3). Split into load (issue early) and commit (cvt + ds_write
// after compute) so HBM latency hides under the MFMA block (T14).
__device__ __forceinline__ void a_load(const float* Ab, long lda, int k0,
                                       int tid, f4* x){
  const int r = tid >> 1, half = tid & 1;
  const float* src = Ab + (long)r*lda + k0 + half*16;
  x[0] = *(const f4*)src;
  x[1] = *(const f4*)(src+4);
  x[2] = *(const f4*)(src+8);
  x[3] = *(const f4*)(src+12);
}

__device__ __forceinline__ void a_commit(const f4* x, h16* lds, int tid){
  const int r = tid >> 1, half = tid & 1;
  h4 a0 = __builtin_convertvector(x[0], h4);
  h4 a1 = __builtin_convertvector(x[1], h4);
  h4 a2 = __builtin_convertvector(x[2], h4);
  h4 a3 = __builtin_convertvector(x[3], h4);
  h8 g0 = __builtin_shufflevector(a0, a1, 0,1,2,3,4,5,6,7);
  h8 g1 = __builtin_shufflevector(a2, a3, 0,1,2,3,4,5,6,7);
  const int s = (r>>1)&3;
  const int kq0 = half*2;
  *(h8*)&lds[r*32 + ((kq0      ^ s)<<3)] = g0;
  *(h8*)&lds[r*32 + (((kq0+1) ^ s)<<3)] = g1;
}

// ---------------------------------------------------------------------------
// Tiled MFMA GEMM: out[r,n] = epi( sum_k A[r,k]*W[n,k] + bias1[n] (+bias2[n]) )
// A: AT [M,K] (lda); W: f16 [N,K] (ld=K); bias f32. 128x128 tile, BK=32.
// Single-barrier bottom-drain K-loop (m248 recipe): stage(t+1) issued before
// compute(t); __syncthreads at loop bottom drains loads that already hid
// their latency under the MFMA block. A stored f16 in LDS in both paths.
// Batched over blockIdx.z. Out row map: idx=(r/rdiv)*stride_b+(r%rdiv)*stride_t+n.
// EPI_GATE: out[idx] *= sigmoid(acc+bias) (read-modify-write).
// ---------------------------------------------------------------------------
template<typename AT, typename OutT, int EPI>
__global__ __launch_bounds__(256) void gemm_k(
    const AT* __restrict__ A, long sA, int lda,
    const h16* __restrict__ W, long sW,
    const float* __restrict__ bias1, long sB1,
    const float* __restrict__ bias2,
    OutT* __restrict__ out, long sOut,
    int K, int rdiv, long stride_b, long stride_t)
{
  constexpr bool AF32 = (sizeof(AT)==4);
  __shared__ __align__(16) h16 As[2][128*32];
  __shared__ __align__(16) h16 Bs[2][128*32];
  const int tid  = threadIdx.x;
  const int lane = tid & 63;
  const int wave = tid >> 6;
  const int z = blockIdx.z;
  const int row0 = blockIdx.x*128;
  const int col0 = blockIdx.y*128;
  const AT*  Ab = A + (long)z*sA + (long)row0*lda;
  const h16* Wb = W + (long)z*sW + (long)col0*K;

  f32x4 acc[4][4];
#pragma unroll
  for(int i=0;i<4;i++)
#pragma unroll
    for(int j=0;j<4;j++)
#pragma unroll
      for(int e=0;e<4;e++) acc[i][j][e]=0.f;

  const int wm = wave >> 1, wn = wave & 1;
  const int lrow = lane & 15, quad = lane >> 4;
  const int nt = K >> 5;

  // ---- prologue: stage tile 0 into buf 0 ----
  f4 ar[4];
  if constexpr (AF32){
    a_load((const float*)Ab, lda, 0, tid, ar);
    a_commit(ar, &As[0][0], tid);
  } else {
    stage_async((const h16*)Ab, lda, 0, &As[0][0], wave, lane);
  }
  stage_async(Wb, K, 0, &Bs[0][0], wave, lane);
  __syncthreads();

  for(int t=0;t<nt;t++){
    const int cur = t&1, nxt = cur^1;
    const bool pf = (t+1 < nt);
    // issue next-tile loads BEFORE compute -- latency hides under MFMAs
    if(pf){
      const int k1 = (t+1)<<5;
      if constexpr (AF32) a_load((const float*)Ab, lda, k1, tid, ar);
      else                stage_async((const h16*)Ab, lda, k1, &As[nxt][0], wave, lane);
      stage_async(Wb, K, k1, &Bs[nxt][0], wave, lane);
    }

    h8 af[4], bfr[4];
#pragma unroll
    for(int i=0;i<4;i++){
      const int ra = wm*64 + i*16 + lrow;
      af[i]  = *(const h8*)&As[cur][ra*32 + ((quad ^ ((ra>>1)&3))<<3)];
      const int rb = wn*64 + i*16 + lrow;
      bfr[i] = *(const h8*)&Bs[cur][rb*32 + ((quad ^ ((rb>>1)&3))<<3)];
    }
#pragma unroll
    for(int i=0;i<4;i++)
#pragma unroll
      for(int j=0;j<4;j++)
        acc[i][j] = __builtin_amdgcn_mfma_f32_16x16x32_f16(af[i], bfr[j], acc[i][j], 0,0,0);

    // commit prefetched A (f32 path): cvt + ds_write into the OTHER buffer.
    // Safe with one barrier: all reads of buf[nxt] ended before the previous
    // __syncthreads (write-after-read ordered by the barrier rendezvous).
    if constexpr (AF32){ if(pf) a_commit(ar, &As[nxt][0], tid); }

    __syncthreads();  // drains vmem (glds DMA landed) + lgkm (ds_writes)
  }

  // epilogue. C/D mapping: col = lane&15, row = (lane>>4)*4 + reg  [m89/m91]
  const float* b1 = bias1 ? bias1 + (long)z*sB1 : nullptr;
  OutT* ob = out + (long)z*sOut;
  float bv[4]; int gcv[4];
#pragma unroll
  for(int j=0;j<4;j++){
    const int gc = col0 + wn*64 + j*16 + lrow;
    gcv[j]=gc;
    float b = b1 ? b1[gc] : 0.f;
    if(bias2) b += bias2[gc];
    bv[j]=b;
  }
#pragma unroll
  for(int i=0;i<4;i++){
#pragma unroll
    for(int e=0;e<4;e++){
      const int gr = row0 + wm*64 + i*16 + quad*4 + e;
      const long rowbase = (long)(gr/rdiv)*stride_b + (long)(gr%rdiv)*stride_t;
#pragma unroll
      for(int j=0;j<4;j++){
        float v = acc[i][j][e] + bv[j];
        const long idx = rowbase + gcv[j];
        if constexpr (EPI==EPI_NONE){
          ob[idx] = (OutT)v;
        } else if constexpr (EPI==EPI_ELU){
          v = v>0.f ? v : expm1f(v);
          ob[idx] = (OutT)v;
        } else { // EPI_GATE
          const float g = 1.f/(1.f+expf(-v));
          const float prev = (float)ob[idx];
          ob[idx] = (OutT)(prev*g);
        }
      }
    }
  }
}

// ---------------------------------------------------------------------------
// Batched f32 -> f16 convert. Block b handles 8192-elem chunk of tensor t
// where blk0[t] <= b < blk0[t+1]. All tensor sizes are multiples of 8192.
// ---------------------------------------------------------------------------
struct CvtArgs { const float* src[8]; h16* dst[8]; int blk0[9]; };

__global__ __launch_bounds__(256) void cvt_k(CvtArgs a){
  int b = blockIdx.x, t = 0;
  while(b >= a.blk0[t+1]) t++;
  const float* s = a.src[t];
  h16* d = a.dst[t];
  const long base = (long)(b - a.blk0[t])*8192 + threadIdx.x*8;
#pragma unroll
  for(int i=0;i<4;i++){
    const long off = base + (long)i*2048;
    *(h8*)(d+off) = ld16f_as_h8(s+off);
  }
}

// ---------------------------------------------------------------------------
// build-H: H_s[r,0:512] = mean_{i<nsel[s]} src[obj_base(r)+sel[s][i]*obj_stride+d]
//          H_s[r,512:1024] = cond[(r/cdiv)*512 + d-512]
// obj_base(r) = (r/rdiv)*stride_hi + (r%rdiv)*stride_lo. All f16.
// ---------------------------------------------------------------------------
struct BuildArgs {
  const h16* src; const h16* cond; h16* H;
  long strideH;
  int rdiv; long stride_hi, stride_lo, obj_stride;
  int cdiv;
  int nsel[16];
  int sel[16][16];
};

__global__ __launch_bounds__(256) void build_h_k(BuildArgs p){
  const int s = blockIdx.z;
  const int tid = threadIdx.x;
  const int r  = blockIdx.x*2 + (tid>>7);
  const int d0 = (tid&127)*8;
  h16* Hp = p.H + (long)s*p.strideH + (long)r*1024 + d0;
  if(d0 < 512){
    const long base = (long)(r/p.rdiv)*p.stride_hi + (long)(r%p.rdiv)*p.stride_lo + d0;
    const int cnt = p.nsel[s];
    float f[8];
#pragma unroll
    for(int e=0;e<8;e++) f[e]=0.f;
    for(int i=0;i<cnt;i++){
      union { h16 h[8]; uint4 q; } v;
      v.q = *(const uint4*)(p.src + base + (long)p.sel[s][i]*p.obj_stride);
#pragma unroll
      for(int e=0;e<8;e++) f[e] += (float)v.h[e];
    }
    const float inv = 1.f/(float)cnt;
    union { h16 h[8]; uint4 q; } o;
#pragma unroll
    for(int e=0;e<8;e++) o.h[e]=(h16)(f[e]*inv);
    *(uint4*)Hp = o.q;
  } else {
    const long cidx = (long)(r/p.cdiv)*512 + (d0-512);
    *(uint4*)Hp = *(const uint4*)(p.cond + cidx);
  }
}

// ---------------------------------------------------------------------------
// LSTM cell (gates f16): gates = xb[b*8+t,:] (+ hW[b,:]); order i,f,g,o.
// ---------------------------------------------------------------------------
__global__ __launch_bounds__(256) void lstm_cell_k(
  const h16* __restrict__ xb, const h16* __restrict__ hW,
  float* __restrict__ c, h16* __restrict__ hout, int t)
{
  const int idx = blockIdx.x*256 + threadIdx.x;
  const int b = idx >> 9, d = idx & 511;
  const h16* xr = xb + (long)(b*8 + t)*2048;
  float gi = (float)xr[d], gf = (float)xr[512+d], gg = (float)xr[1024+d], go = (float)xr[1536+d];
  if(hW){
    const h16* hr = hW + (long)b*2048;
    gi += (float)hr[d]; gf += (float)hr[512+d]; gg += (float)hr[1024+d]; go += (float)hr[1536+d];
  }
  const float cp = (t==0)?0.f:c[idx];
  const float si = 1.f/(1.f+expf(-gi));
  const float sf = 1.f/(1.f+expf(-gf));
  const float so = 1.f/(1.f+expf(-go));
  const float cn = sf*cp + si*tanhf(gg);
  const float hn = so*tanhf(cn);
  c[idx]=cn; hout[idx]=(h16)hn;
}

// ---------------------------------------------------------------------------
// Host-side exact replication of np.random.RandomState(0) subset choices
// (verified R2). choice(N,1,replace=False) == permutation(N)[0].
// ---------------------------------------------------------------------------
namespace {

struct MT19937 {
  u32 mt[624]; int mti;
  void seed(u32 s){
    mt[0]=s;
    for(int i=1;i<624;i++) mt[i]=1812433253u*(mt[i-1]^(mt[i-1]>>30))+(u32)i;
    mti=624;
  }
  u32 next(){
    if(mti>=624){
      for(int i=0;i<624;i++){
        u32 y=(mt[i]&0x80000000u)|(mt[(i+1)%624]&0x7fffffffu);
        mt[i]=mt[(i+397)%624]^(y>>1)^((y&1u)?2567483615u:0u);
      }
      mti=0;
    }
    u32 y=mt[mti++];
    y^=y>>11; y^=(y<<7)&2636928640u; y^=(y<<15)&4022730752u; y^=y>>18;
    return y;
  }
};

static unsigned long long rand_interval(MT19937& r, unsigned long long mx){
  if(!mx) return 0;
  unsigned long long mask=mx;
  mask|=mask>>1; mask|=mask>>2; mask|=mask>>4; mask|=mask>>8; mask|=mask>>16; mask|=mask>>32;
  unsigned long long v;
  do { v = (unsigned long long)r.next() & mask; } while (v > mx);
  return v;
}

static long choice_one(MT19937& r, long N){
  std::vector<int> a((size_t)N);
  for(long i=0;i<N;i++) a[(size_t)i]=(int)i;
  for(long i=N-1;i>=1;i--){
    long j=(long)rand_interval(r,(unsigned long long)i);
    int t=a[(size_t)i]; a[(size_t)i]=a[(size_t)j]; a[(size_t)j]=t;
  }
  return a[0];
}

struct SelSet { int cnt; int idx[16]; };

static void compute_sels(SelSet* l1, SelSet* l2, SelSet* l3, SelSet* l4){
  long long Bn[20][20] = {};
  for(int i=0;i<20;i++){ Bn[i][0]=1; for(int j=1;j<=i;j++) Bn[i][j]=Bn[i-1][j-1]+Bn[i-1][j]; }
  MT19937 rng; rng.seed(0);
  auto dolevel=[&](int n, int nsc, SelSet* outs){
    for(int s=0;s<nsc;s++){
      const int scale = n-1-s;
      const long long N = Bn[n][scale];
      long long rem = (long long)choice_one(rng,(long)N);
      int x=0;
      for(int pos=0;pos<scale;pos++){
        for(int v=x;;v++){
          const long long c = Bn[n-1-v][scale-1-pos];
          if(rem < c){ outs[s].idx[pos]=v; x=v+1; break; }
          rem -= c;
        }
      }
      outs[s].cnt=scale;
    }
  };
  dolevel(16,14,l1);
  dolevel(14,12,l2);
  dolevel(8, 6, l3);
  dolevel(6, 4, l4);
}

} // namespace

// ---------------------------------------------------------------------------
extern "C" void kernel_launch(void* const* d_in, const int* in_sizes, int n_in,
                              void* d_out, int out_size, void* d_ws, size_t ws_size,
                              hipStream_t stream) {
  (void)in_sizes; (void)n_in; (void)out_size; (void)ws_size;

  const float* app  = (const float*)d_in[0];
  const float* mot  = (const float*)d_in[1];
  const float* ques = (const float*)d_in[2];
  const float* Wq =(const float*)d_in[3];  const float* bq =(const float*)d_in[4];
  const float* Wm =(const float*)d_in[5];  const float* bm =(const float*)d_in[6];
  const float* Wa =(const float*)d_in[7];  const float* ba =(const float*)d_in[8];
  const float* Wvm=(const float*)d_in[9];  const float* bvm=(const float*)d_in[10];
  const float* Wih=(const float*)d_in[11]; const float* Whh=(const float*)d_in[12];
  const float* bih=(const float*)d_in[13]; const float* bhh=(const float*)d_in[14];
  const float* W1 =(const float*)d_in[15]; const float* b1 =(const float*)d_in[16];
  const float* W2 =(const float*)d_in[17]; const float* b2 =(const float*)d_in[18];
  const float* gW2=(const float*)d_in[19]; const float* gb2=(const float*)d_in[20];
  const float* W3 =(const float*)d_in[21]; const float* b3 =(const float*)d_in[22];
  const float* W4 =(const float*)d_in[23]; const float* b4 =(const float*)d_in[24];
  const float* gW4=(const float*)d_in[25]; const float* gb4=(const float*)d_in[26];

  // ---- tight workspace layout (peak 92,536,832 B < proven-safe 94,109,696) --
  char* wsp = (char*)d_ws;
  h16* app_proj = (h16*)(wsp + 0);          // 16 MiB; live projs -> L1 build
  h16* crnm     = (h16*)(wsp + 16777216);   // 14 MiB; L1 gemm -> L2 build
  h16* crnq     = (h16*)(wsp + 31457280);   // 12 MiB; L2 -> L3 build
  h16* crnvm    = (h16*)(wsp + 44040192);   //  9 MiB; L3 -> L4 build
  h16* Hbuf     = (h16*)(wsp + 53477376);   // 12 MiB; per-level chunks
  char* Warena  =        wsp + 66060288;    // 24 MiB; phase-reused
  h16* mot_proj = (h16*)(wsp + 91226112);   // 1 MiB
  h16* q_proj   = (h16*)(wsp + 92274688);   // 128 KiB; live -> L4 build
  h16* vm_proj  = (h16*)(wsp + 92405760);   // 128 KiB; live -> L3 build

  // LSTM scratch inside crnm region (crnm written after LSTM completes)
  h16*  xb16 = (h16*)((char*)crnm + 0);        // [1024,2048] f16
  h16*  hWb  = (h16*)((char*)crnm + 4194304);  // [128,2048] f16
  float* cbuf= (float*)((char*)crnm + 4718592);// [128,512] f32
  h16*  h0   = (h16*)((char*)crnm + 4980736);
  h16*  h1   = (h16*)((char*)crnm + 5111808);

  // W-arena phase A: early weights + activations (dead before W1 cvt)
  h16* Wa16  = (h16*)(Warena + 0);
  h16* Wm16  = (h16*)(Warena + 2097152);
  h16* Wq16  = (h16*)(Warena + 4194304);
  h16* Wvm16 = (h16*)(Warena + 4718592);
  h16* Wih16 = (h16*)(Warena + 5242880);
  h16* Whh16 = (h16*)(Warena + 13631488);
  h16* mot16 = (h16*)(Warena + 15728640);
  h16* ques16= (h16*)(Warena + 19922944);
  // phase B: W1_16 (14 slices); phase C: W2_16+gW2_16; phase D: W3/W4/gW4
  h16* W1_16 = (h16*)(Warena + 0);
  h16* W2_16 = (h16*)(Warena + 0);
  h16* gW2_16= (h16*)(Warena + 12582912);
  h16* W3_16 = (h16*)(Warena + 0);
  h16* W4_16 = (h16*)(Warena + 6291456);
  h16* gW4_16= (h16*)(Warena + 10485760);

  float* outp = (float*)d_out;

  SelSet s1[14], s2[12], s3[6], s4[4];
  compute_sels(s1,s2,s3,s4);

  auto cvt = [&](std::initializer_list<const float*> srcs,
                 std::initializer_list<h16*> dsts,
                 std::initializer_list<long> ns){
    CvtArgs a{}; int t=0, blk=0; a.blk0[0]=0;
    auto si=srcs.begin(); auto di=dsts.begin(); auto ni=ns.begin();
    for(; si!=srcs.end(); ++si,++di,++ni,++t){
      a.src[t]=*si; a.dst[t]=*di; blk += (int)(*ni/8192); a.blk0[t+1]=blk;
    }
    for(int i=t+1;i<=8;i++) a.blk0[i]=blk;
    cvt_k<<<dim3(blk),256,0,stream>>>(a);
  };

  // ---- phase 0: early converts -----------------------------------------
  cvt({Wa, Wm, Wq, Wvm, Wih, Whh, mot, ques},
      {Wa16, Wm16, Wq16, Wvm16, Wih16, Whh16, mot16, ques16},
      {1048576, 1048576, 262144, 262144, 4194304, 1048576, 2097152, 65536});

  // ---- phase 1: projections --------------------------------------------
  gemm_k<float,h16,EPI_NONE><<<dim3(128,4,1),256,0,stream>>>(
      app,0,2048, Wa16,0, ba,0, nullptr, app_proj,0, 2048, 16384,0,512);
  gemm_k<h16,h16,EPI_NONE><<<dim3(8,4,1),256,0,stream>>>(
      mot16,0,2048, Wm16,0, bm,0, nullptr, mot_proj,0, 2048, 1024,0,512);
  gemm_k<h16,h16,EPI_NONE><<<dim3(1,4,1),256,0,stream>>>(
      ques16,0,512, Wq16,0, bq,0, nullptr, q_proj,0, 512, 128,0,512);
  gemm_k<h16,h16,EPI_NONE><<<dim3(8,16,1),256,0,stream>>>(
      mot16,0,2048, Wih16,0, bih,0, bhh, xb16,0, 2048, 1024,0,2048);

  // ---- phase 2: LSTM (moved before CRN; dataflow-independent) ----------
  h16* hping[2] = {h0, h1};
  lstm_cell_k<<<dim3(256),256,0,stream>>>(xb16, nullptr, cbuf, hping[0], 0);
  for(int t=1;t<8;t++){
    gemm_k<h16,h16,EPI_NONE><<<dim3(1,16,1),256,0,stream>>>(
        hping[(t-1)&1],0,512, Whh16,0, nullptr,0, nullptr,
        hWb,0, 512, 128,0,2048);
    lstm_cell_k<<<dim3(256),256,0,stream>>>(xb16, hWb, cbuf, hping[t&1], t);
  }
  gemm_k<h16,h16,EPI_NONE><<<dim3(1,4,1),256,0,stream>>>(
      hping[1],0,512, Wvm16,0, bvm,0, nullptr, vm_proj,0, 512, 128,0,512);

  auto fill_chunk=[&](BuildArgs& a, const SelSet* ss, int z0, int nz){
    for(int s=0;s<nz;s++){ a.nsel[s]=ss[z0+s].cnt;
      for(int i=0;i<ss[z0+s].cnt;i++) a.sel[s][i]=ss[z0+s].idx[i]; }
  };

  // ---- CRN level 1 (chunks 6,6,2): objs=app_proj, cond=mot_proj --------
  cvt({W1+524288},{W1_16},{7340032});
  {
    const int z0s[3]={0,6,12}, nzs[3]={6,6,2};
    for(int ch=0;ch<3;ch++){
      const int z0=z0s[ch], nz=nzs[ch];
      BuildArgs a = {}; a.src=app_proj; a.cond=mot_proj; a.H=Hbuf;
      a.strideH=1048576; a.rdiv=1024; a.stride_hi=0; a.stride_lo=8192;
      a.obj_stride=512; a.cdiv=1; fill_chunk(a,s1,z0,nz);
      build_h_k<<<dim3(512,1,nz),256,0,stream>>>(a);
      gemm_k<h16,h16,EPI_ELU><<<dim3(8,4,nz),256,0,stream>>>(
          Hbuf,1048576,1024, W1_16+(long)z0*524288,524288,
          b1+(long)(z0+1)*512,512, nullptr,
          crnm+(long)z0*524288,524288, 1024, 1024,0,512);
    }
  }
  // ---- CRN level 2 (chunks 6,6; gated): objs=crnm, cond=q_proj ---------
  cvt({W2+524288, gW2+524288},{W2_16, gW2_16},{6291456, 6291456});
  {
    const int z0s[2]={0,6}, nzs[2]={6,6};
    for(int ch=0;ch<2;ch++){
      const int z0=z0s[ch], nz=nzs[ch];
      BuildArgs a = {}; a.src=crnm; a.cond=q_proj; a.H=Hbuf;
      a.strideH=1048576; a.rdiv=1024; a.stride_hi=0; a.stride_lo=512;
      a.obj_stride=524288; a.cdiv=8; fill_chunk(a,s2,z0,nz);
      build_h_k<<<dim3(512,1,nz),256,0,stream>>>(a);
      gemm_k<h16,h16,EPI_ELU><<<dim3(8,4,nz),256,0,stream>>>(
          Hbuf,1048576,1024, W2_16+(long)z0*524288,524288,
          b2+(long)(z0+1)*512,512, nullptr,
          crnq+(long)z0*524288,524288, 1024, 1024,0,512);
      gemm_k<h16,h16,EPI_GATE><<<dim3(8,4,nz),256,0,stream>>>(
          Hbuf,1048576,1024, gW2_16+(long)z0*524288,524288,
          gb2+(long)(z0+1)*512,512, nullptr,
          crnq+(long)z0*524288,524288, 1024, 1024,0,512);
    }
  }
  // ---- CRN level 3 (chunks 4,2): objs=crnq[t][b*8+c], cond=vm_proj -----
  cvt({W3+524288, W4+524288, gW4+524288},{W3_16, W4_16, gW4_16},
      {3145728, 2097152, 2097152});
  {
    const int z0s[2]={0,4}, nzs[2]={4,2};
    for(int ch=0;ch<2;ch++){
      const int z0=z0s[ch], nz=nzs[ch];
      BuildArgs a = {}; a.src=crnq; a.cond=vm_proj; a.H=Hbuf;
      a.strideH=1572864; a.rdiv=12; a.stride_hi=4096; a.stride_lo=524288;
      a.obj_stride=512; a.cdiv=12; fill_chunk(a,s3,z0,nz);
      build_h_k<<<dim3(768,1,nz),256,0,stream>>>(a);
      gemm_k<h16,h16,EPI_ELU><<<dim3(12,4,nz),256,0,stream>>>(
          Hbuf,1572864,1024, W3_16+(long)z0*524288,524288,
          b3+(long)(z0+1)*512,512, nullptr,
          crnvm+(long)z0*786432,786432, 1024, 1536,0,512);
    }
  }
  // ---- CRN level 4 (single chunk, gated) -> d_out (f32) ----------------
  {
    BuildArgs a = {}; a.src=crnvm; a.cond=q_proj; a.H=Hbuf;
    a.strideH=1572864; a.rdiv=1536; a.stride_hi=0; a.stride_lo=512;
    a.obj_stride=786432; a.cdiv=12; fill_chunk(a,s4,0,4);
    build_h_k<<<dim3(768,1,4),256,0,stream>>>(a);
    // out[b, s*12+t, d]: r=b*12+t -> (r/12)*24576 + (r%12)*512, +s*6144
    gemm_k<h16,float,EPI_ELU><<<dim3(12,4,4),256,0,stream>>>(
        Hbuf,1572864,1024, W4_16,524288, b4+512,512, nullptr,
        outp,6144, 1024, 12,24576,512);
    gemm_k<h16,float,EPI_GATE><<<dim3(12,4,4),256,0,stream>>>(
        Hbuf,1572864,1024, gW4_16,524288, gb4+512,512, nullptr,
        outp,6144, 1024, 12,24576,512);
  }
}

// Round 3
// 850.765 us; speedup vs baseline: 1.1491x; 1.1491x over previous
//
#include <hip/hip_runtime.h>
#include <vector>
#include <cstdint>
#include <cstddef>

// ---------------------------------------------------------------------------
// EncoderVidCRN on MI355X. Global tensors f32; MFMA in f16 (verified R2:
// absmax 2e-3 vs 9.9e-3 threshold). Weights pre-converted to f16; W-side and
// f16 A-sides stage via global_load_lds; f32 A-side reg-staged (zero-conflict
// swizzle). R6 (this round): tile 128x128 -> 64x128, waves 2x2 (wave-tile
// 32x64, acc[2][4]). Rationale: MfmaUtil pinned at 13% across three loop
// structures with both pipes idle and Occupancy 20% == latency-bound at
// 2 blocks/CU (m102 occupancy curve: 1/CU->320TF, 4/CU->833TF). Doubling the
// grid (app GEMM 512->1024 blocks = 4/CU; CRN GEMMs 0.75->1.5/CU) buys TLP;
// LDS 24KB/block, VGPR ~56 so occupancy is grid-limited only.
// K-loop: single-barrier bottom-drain dbuf (m248 recipe), unchanged from R5.
// ---------------------------------------------------------------------------

typedef unsigned short u16;
typedef unsigned int u32;

typedef _Float16 h16;
typedef h16  h8 __attribute__((ext_vector_type(8)));
typedef h16  h4 __attribute__((ext_vector_type(4)));
typedef float f4 __attribute__((ext_vector_type(4)));
typedef float f32x4 __attribute__((ext_vector_type(4)));

enum { EPI_NONE=0, EPI_ELU=1, EPI_GATE=2 };

__device__ __forceinline__ h8 ld16f_as_h8(const float* p){
  f4 x0 = *(const f4*)p, x1 = *(const f4*)(p+4);
  h4 a = __builtin_convertvector(x0, h4);
  h4 b = __builtin_convertvector(x1, h4);
  return __builtin_shufflevector(a, b, 0,1,2,3,4,5,6,7);
}

// f16 direct-to-LDS path (m97). LDS dest = wave-uniform base + lane*16B:
// lane L of chunk c lands at elem c*512 + L*8 = row(c*16+(L>>2))*32 + (L&3)*8,
// i.e. slot L&3; so lane loads global granule kq = (L&3) ^ s(row) so that
// the fragment-read swizzle (slot = quad ^ s(row)) recovers it.
// CPW = chunks (of 16 rows) per wave: A-tile(64 rows)=1, B-tile(128 rows)=2.
template<int CPW>
__device__ __forceinline__ void stage_async(const h16* base, long ld, int k0,
                                            h16* lds, int wave, int lane){
#pragma unroll
  for(int cc=0;cc<CPW;cc++){
    const int c = wave*CPW+cc;
    const int r = c*16 + (lane>>2);
    const int kq = (lane&3) ^ ((r>>1)&3);
    const h16* g = base + (long)r*ld + k0 + kq*8;
    __builtin_amdgcn_global_load_lds(
        (const __attribute__((address_space(1))) void*)g,
        (__attribute__((address_space(3))) void*)&lds[c*512], 16, 0, 0);
  }
}

// f32 register-staged path (R3-proven zero-conflict layout), 64-row tile:
// thread t -> row r = t>>2, granule q = t&3 (8 f32 = 32B load). Granule q of
// row r stored at slot q ^ ((r>>1)&3). Split into load (issue early) and
// commit (cvt + ds_write after compute) so HBM latency hides under MFMAs.
__device__ __forceinline__ void a_load(const float* Ab, long lda, int k0,
                                       int tid, f4* x){
  const int r = tid >> 2, q = tid & 3;
  const float* src = Ab + (long)r*lda + k0 + q*8;
  x[0] = *(const f4*)src;
  x[1] = *(const f4*)(src+4);
}

__device__ __forceinline__ void a_commit(const f4* x, h16* lds, int tid){
  const int r = tid >> 2, q = tid & 3;
  h4 a0 = __builtin_convertvector(x[0], h4);
  h4 a1 = __builtin_convertvector(x[1], h4);
  h8 g = __builtin_shufflevector(a0, a1, 0,1,2,3,4,5,6,7);
  const int s = (r>>1)&3;
  *(h8*)&lds[r*32 + ((q ^ s)<<3)] = g;
}

// ---------------------------------------------------------------------------
// Tiled MFMA GEMM: out[r,n] = epi( sum_k A[r,k]*W[n,k] + bias1[n] (+bias2[n]) )
// A: AT [M,K] (lda, M % 64 == 0); W: f16 [N,K] (ld=K); bias f32.
// 64x128 tile, BK=32, 4 waves as 2x2 (wave-tile 32 rows x 64 cols, acc[2][4]).
// Single-barrier bottom-drain dbuf K-loop. Batched over blockIdx.z.
// Out row map: idx=(r/rdiv)*stride_b+(r%rdiv)*stride_t+n.
// EPI_GATE: out[idx] *= sigmoid(acc+bias) (read-modify-write).
// ---------------------------------------------------------------------------
template<typename AT, typename OutT, int EPI>
__global__ __launch_bounds__(256) void gemm_k(
    const AT* __restrict__ A, long sA, int lda,
    const h16* __restrict__ W, long sW,
    const float* __restrict__ bias1, long sB1,
    const float* __restrict__ bias2,
    OutT* __restrict__ out, long sOut,
    int K, int rdiv, long stride_b, long stride_t)
{
  constexpr bool AF32 = (sizeof(AT)==4);
  __shared__ __align__(16) h16 As[2][64*32];
  __shared__ __align__(16) h16 Bs[2][128*32];
  const int tid  = threadIdx.x;
  const int lane = tid & 63;
  const int wave = tid >> 6;
  const int z = blockIdx.z;
  const int row0 = blockIdx.x*64;
  const int col0 = blockIdx.y*128;
  const AT*  Ab = A + (long)z*sA + (long)row0*lda;
  const h16* Wb = W + (long)z*sW + (long)col0*K;

  f32x4 acc[2][4];
#pragma unroll
  for(int i=0;i<2;i++)
#pragma unroll
    for(int j=0;j<4;j++)
#pragma unroll
      for(int e=0;e<4;e++) acc[i][j][e]=0.f;

  const int wm = wave >> 1, wn = wave & 1;
  const int lrow = lane & 15, quad = lane >> 4;
  const int nt = K >> 5;

  // ---- prologue: stage tile 0 into buf 0 ----
  f4 ar[2];
  if constexpr (AF32){
    a_load((const float*)Ab, lda, 0, tid, ar);
    a_commit(ar, &As[0][0], tid);
  } else {
    stage_async<1>((const h16*)Ab, lda, 0, &As[0][0], wave, lane);
  }
  stage_async<2>(Wb, K, 0, &Bs[0][0], wave, lane);
  __syncthreads();

  for(int t=0;t<nt;t++){
    const int cur = t&1, nxt = cur^1;
    const bool pf = (t+1 < nt);
    // issue next-tile loads BEFORE compute -- latency hides under MFMAs
    if(pf){
      const int k1 = (t+1)<<5;
      if constexpr (AF32) a_load((const float*)Ab, lda, k1, tid, ar);
      else                stage_async<1>((const h16*)Ab, lda, k1, &As[nxt][0], wave, lane);
      stage_async<2>(Wb, K, k1, &Bs[nxt][0], wave, lane);
    }

    h8 af[2], bfr[4];
#pragma unroll
    for(int i=0;i<2;i++){
      const int ra = wm*32 + i*16 + lrow;
      af[i]  = *(const h8*)&As[cur][ra*32 + ((quad ^ ((ra>>1)&3))<<3)];
    }
#pragma unroll
    for(int j=0;j<4;j++){
      const int rb = wn*64 + j*16 + lrow;
      bfr[j] = *(const h8*)&Bs[cur][rb*32 + ((quad ^ ((rb>>1)&3))<<3)];
    }
#pragma unroll
    for(int i=0;i<2;i++)
#pragma unroll
      for(int j=0;j<4;j++)
        acc[i][j] = __builtin_amdgcn_mfma_f32_16x16x32_f16(af[i], bfr[j], acc[i][j], 0,0,0);

    // commit prefetched A (f32 path): cvt + ds_write into the OTHER buffer.
    // Safe with one barrier: all reads of buf[nxt] ended before the previous
    // __syncthreads (write-after-read ordered by the barrier rendezvous).
    if constexpr (AF32){ if(pf) a_commit(ar, &As[nxt][0], tid); }

    __syncthreads();  // drains vmem (glds DMA landed) + lgkm (ds_writes)
  }

  // epilogue. C/D mapping: col = lane&15, row = (lane>>4)*4 + reg  [m89/m91]
  const float* b1 = bias1 ? bias1 + (long)z*sB1 : nullptr;
  OutT* ob = out + (long)z*sOut;
  float bv[4]; int gcv[4];
#pragma unroll
  for(int j=0;j<4;j++){
    const int gc = col0 + wn*64 + j*16 + lrow;
    gcv[j]=gc;
    float b = b1 ? b1[gc] : 0.f;
    if(bias2) b += bias2[gc];
    bv[j]=b;
  }
#pragma unroll
  for(int i=0;i<2;i++){
#pragma unroll
    for(int e=0;e<4;e++){
      const int gr = row0 + wm*32 + i*16 + quad*4 + e;
      const long rowbase = (long)(gr/rdiv)*stride_b + (long)(gr%rdiv)*stride_t;
#pragma unroll
      for(int j=0;j<4;j++){
        float v = acc[i][j][e] + bv[j];
        const long idx = rowbase + gcv[j];
        if constexpr (EPI==EPI_NONE){
          ob[idx] = (OutT)v;
        } else if constexpr (EPI==EPI_ELU){
          v = v>0.f ? v : expm1f(v);
          ob[idx] = (OutT)v;
        } else { // EPI_GATE
          const float g = 1.f/(1.f+expf(-v));
          const float prev = (float)ob[idx];
          ob[idx] = (OutT)(prev*g);
        }
      }
    }
  }
}

// ---------------------------------------------------------------------------
// Batched f32 -> f16 convert. Block b handles 8192-elem chunk of tensor t
// where blk0[t] <= b < blk0[t+1]. All tensor sizes are multiples of 8192.
// ---------------------------------------------------------------------------
struct CvtArgs { const float* src[8]; h16* dst[8]; int blk0[9]; };

__global__ __launch_bounds__(256) void cvt_k(CvtArgs a){
  int b = blockIdx.x, t = 0;
  while(b >= a.blk0[t+1]) t++;
  const float* s = a.src[t];
  h16* d = a.dst[t];
  const long base = (long)(b - a.blk0[t])*8192 + threadIdx.x*8;
#pragma unroll
  for(int i=0;i<4;i++){
    const long off = base + (long)i*2048;
    *(h8*)(d+off) = ld16f_as_h8(s+off);
  }
}

// ---------------------------------------------------------------------------
// build-H: H_s[r,0:512] = mean_{i<nsel[s]} src[obj_base(r)+sel[s][i]*obj_stride+d]
//          H_s[r,512:1024] = cond[(r/cdiv)*512 + d-512]
// obj_base(r) = (r/rdiv)*stride_hi + (r%rdiv)*stride_lo. All f16.
// ---------------------------------------------------------------------------
struct BuildArgs {
  const h16* src; const h16* cond; h16* H;
  long strideH;
  int rdiv; long stride_hi, stride_lo, obj_stride;
  int cdiv;
  int nsel[16];
  int sel[16][16];
};

__global__ __launch_bounds__(256) void build_h_k(BuildArgs p){
  const int s = blockIdx.z;
  const int tid = threadIdx.x;
  const int r  = blockIdx.x*2 + (tid>>7);
  const int d0 = (tid&127)*8;
  h16* Hp = p.H + (long)s*p.strideH + (long)r*1024 + d0;
  if(d0 < 512){
    const long base = (long)(r/p.rdiv)*p.stride_hi + (long)(r%p.rdiv)*p.stride_lo + d0;
    const int cnt = p.nsel[s];
    float f[8];
#pragma unroll
    for(int e=0;e<8;e++) f[e]=0.f;
    for(int i=0;i<cnt;i++){
      union { h16 h[8]; uint4 q; } v;
      v.q = *(const uint4*)(p.src + base + (long)p.sel[s][i]*p.obj_stride);
#pragma unroll
      for(int e=0;e<8;e++) f[e] += (float)v.h[e];
    }
    const float inv = 1.f/(float)cnt;
    union { h16 h[8]; uint4 q; } o;
#pragma unroll
    for(int e=0;e<8;e++) o.h[e]=(h16)(f[e]*inv);
    *(uint4*)Hp = o.q;
  } else {
    const long cidx = (long)(r/p.cdiv)*512 + (d0-512);
    *(uint4*)Hp = *(const uint4*)(p.cond + cidx);
  }
}

// ---------------------------------------------------------------------------
// LSTM cell (gates f16): gates = xb[b*8+t,:] (+ hW[b,:]); order i,f,g,o.
// ---------------------------------------------------------------------------
__global__ __launch_bounds__(256) void lstm_cell_k(
  const h16* __restrict__ xb, const h16* __restrict__ hW,
  float* __restrict__ c, h16* __restrict__ hout, int t)
{
  const int idx = blockIdx.x*256 + threadIdx.x;
  const int b = idx >> 9, d = idx & 511;
  const h16* xr = xb + (long)(b*8 + t)*2048;
  float gi = (float)xr[d], gf = (float)xr[512+d], gg = (float)xr[1024+d], go = (float)xr[1536+d];
  if(hW){
    const h16* hr = hW + (long)b*2048;
    gi += (float)hr[d]; gf += (float)hr[512+d]; gg += (float)hr[1024+d]; go += (float)hr[1536+d];
  }
  const float cp = (t==0)?0.f:c[idx];
  const float si = 1.f/(1.f+expf(-gi));
  const float sf = 1.f/(1.f+expf(-gf));
  const float so = 1.f/(1.f+expf(-go));
  const float cn = sf*cp + si*tanhf(gg);
  const float hn = so*tanhf(cn);
  c[idx]=cn; hout[idx]=(h16)hn;
}

// ---------------------------------------------------------------------------
// Host-side exact replication of np.random.RandomState(0) subset choices
// (verified R2). choice(N,1,replace=False) == permutation(N)[0].
// ---------------------------------------------------------------------------
namespace {

struct MT19937 {
  u32 mt[624]; int mti;
  void seed(u32 s){
    mt[0]=s;
    for(int i=1;i<624;i++) mt[i]=1812433253u*(mt[i-1]^(mt[i-1]>>30))+(u32)i;
    mti=624;
  }
  u32 next(){
    if(mti>=624){
      for(int i=0;i<624;i++){
        u32 y=(mt[i]&0x80000000u)|(mt[(i+1)%624]&0x7fffffffu);
        mt[i]=mt[(i+397)%624]^(y>>1)^((y&1u)?2567483615u:0u);
      }
      mti=0;
    }
    u32 y=mt[mti++];
    y^=y>>11; y^=(y<<7)&2636928640u; y^=(y<<15)&4022730752u; y^=y>>18;
    return y;
  }
};

static unsigned long long rand_interval(MT19937& r, unsigned long long mx){
  if(!mx) return 0;
  unsigned long long mask=mx;
  mask|=mask>>1; mask|=mask>>2; mask|=mask>>4; mask|=mask>>8; mask|=mask>>16; mask|=mask>>32;
  unsigned long long v;
  do { v = (unsigned long long)r.next() & mask; } while (v > mx);
  return v;
}

static long choice_one(MT19937& r, long N){
  std::vector<int> a((size_t)N);
  for(long i=0;i<N;i++) a[(size_t)i]=(int)i;
  for(long i=N-1;i>=1;i--){
    long j=(long)rand_interval(r,(unsigned long long)i);
    int t=a[(size_t)i]; a[(size_t)i]=a[(size_t)j]; a[(size_t)j]=t;
  }
  return a[0];
}

struct SelSet { int cnt; int idx[16]; };

static void compute_sels(SelSet* l1, SelSet* l2, SelSet* l3, SelSet* l4){
  long long Bn[20][20] = {};
  for(int i=0;i<20;i++){ Bn[i][0]=1; for(int j=1;j<=i;j++) Bn[i][j]=Bn[i-1][j-1]+Bn[i-1][j]; }
  MT19937 rng; rng.seed(0);
  auto dolevel=[&](int n, int nsc, SelSet* outs){
    for(int s=0;s<nsc;s++){
      const int scale = n-1-s;
      const long long N = Bn[n][scale];
      long long rem = (long long)choice_one(rng,(long)N);
      int x=0;
      for(int pos=0;pos<scale;pos++){
        for(int v=x;;v++){
          const long long c = Bn[n-1-v][scale-1-pos];
          if(rem < c){ outs[s].idx[pos]=v; x=v+1; break; }
          rem -= c;
        }
      }
      outs[s].cnt=scale;
    }
  };
  dolevel(16,14,l1);
  dolevel(14,12,l2);
  dolevel(8, 6, l3);
  dolevel(6, 4, l4);
}

} // namespace

// ---------------------------------------------------------------------------
extern "C" void kernel_launch(void* const* d_in, const int* in_sizes, int n_in,
                              void* d_out, int out_size, void* d_ws, size_t ws_size,
                              hipStream_t stream) {
  (void)in_sizes; (void)n_in; (void)out_size; (void)ws_size;

  const float* app  = (const float*)d_in[0];
  const float* mot  = (const float*)d_in[1];
  const float* ques = (const float*)d_in[2];
  const float* Wq =(const float*)d_in[3];  const float* bq =(const float*)d_in[4];
  const float* Wm =(const float*)d_in[5];  const float* bm =(const float*)d_in[6];
  const float* Wa =(const float*)d_in[7];  const float* ba =(const float*)d_in[8];
  const float* Wvm=(const float*)d_in[9];  const float* bvm=(const float*)d_in[10];
  const float* Wih=(const float*)d_in[11]; const float* Whh=(const float*)d_in[12];
  const float* bih=(const float*)d_in[13]; const float* bhh=(const float*)d_in[14];
  const float* W1 =(const float*)d_in[15]; const float* b1 =(const float*)d_in[16];
  const float* W2 =(const float*)d_in[17]; const float* b2 =(const float*)d_in[18];
  const float* gW2=(const float*)d_in[19]; const float* gb2=(const float*)d_in[20];
  const float* W3 =(const float*)d_in[21]; const float* b3 =(const float*)d_in[22];
  const float* W4 =(const float*)d_in[23]; const float* b4 =(const float*)d_in[24];
  const float* gW4=(const float*)d_in[25]; const float* gb4=(const float*)d_in[26];

  // ---- tight workspace layout (peak 92,536,832 B < proven-safe 94,109,696) --
  char* wsp = (char*)d_ws;
  h16* app_proj = (h16*)(wsp + 0);          // 16 MiB; live projs -> L1 build
  h16* crnm     = (h16*)(wsp + 16777216);   // 14 MiB; L1 gemm -> L2 build
  h16* crnq     = (h16*)(wsp + 31457280);   // 12 MiB; L2 -> L3 build
  h16* crnvm    = (h16*)(wsp + 44040192);   //  9 MiB; L3 -> L4 build
  h16* Hbuf     = (h16*)(wsp + 53477376);   // 12 MiB; per-level chunks
  char* Warena  =        wsp + 66060288;    // 24 MiB; phase-reused
  h16* mot_proj = (h16*)(wsp + 91226112);   // 1 MiB
  h16* q_proj   = (h16*)(wsp + 92274688);   // 128 KiB; live -> L4 build
  h16* vm_proj  = (h16*)(wsp + 92405760);   // 128 KiB; live -> L3 build

  // LSTM scratch inside crnm region (crnm written after LSTM completes)
  h16*  xb16 = (h16*)((char*)crnm + 0);        // [1024,2048] f16
  h16*  hWb  = (h16*)((char*)crnm + 4194304);  // [128,2048] f16
  float* cbuf= (float*)((char*)crnm + 4718592);// [128,512] f32
  h16*  h0   = (h16*)((char*)crnm + 4980736);
  h16*  h1   = (h16*)((char*)crnm + 5111808);

  // W-arena phase A: early weights + activations (dead before W1 cvt)
  h16* Wa16  = (h16*)(Warena + 0);
  h16* Wm16  = (h16*)(Warena + 2097152);
  h16* Wq16  = (h16*)(Warena + 4194304);
  h16* Wvm16 = (h16*)(Warena + 4718592);
  h16* Wih16 = (h16*)(Warena + 5242880);
  h16* Whh16 = (h16*)(Warena + 13631488);
  h16* mot16 = (h16*)(Warena + 15728640);
  h16* ques16= (h16*)(Warena + 19922944);
  // phase B: W1_16 (14 slices); phase C: W2_16+gW2_16; phase D: W3/W4/gW4
  h16* W1_16 = (h16*)(Warena + 0);
  h16* W2_16 = (h16*)(Warena + 0);
  h16* gW2_16= (h16*)(Warena + 12582912);
  h16* W3_16 = (h16*)(Warena + 0);
  h16* W4_16 = (h16*)(Warena + 6291456);
  h16* gW4_16= (h16*)(Warena + 10485760);

  float* outp = (float*)d_out;

  SelSet s1[14], s2[12], s3[6], s4[4];
  compute_sels(s1,s2,s3,s4);

  auto cvt = [&](std::initializer_list<const float*> srcs,
                 std::initializer_list<h16*> dsts,
                 std::initializer_list<long> ns){
    CvtArgs a{}; int t=0, blk=0; a.blk0[0]=0;
    auto si=srcs.begin(); auto di=dsts.begin(); auto ni=ns.begin();
    for(; si!=srcs.end(); ++si,++di,++ni,++t){
      a.src[t]=*si; a.dst[t]=*di; blk += (int)(*ni/8192); a.blk0[t+1]=blk;
    }
    for(int i=t+1;i<=8;i++) a.blk0[i]=blk;
    cvt_k<<<dim3(blk),256,0,stream>>>(a);
  };

  // ---- phase 0: early converts -----------------------------------------
  cvt({Wa, Wm, Wq, Wvm, Wih, Whh, mot, ques},
      {Wa16, Wm16, Wq16, Wvm16, Wih16, Whh16, mot16, ques16},
      {1048576, 1048576, 262144, 262144, 4194304, 1048576, 2097152, 65536});

  // ---- phase 1: projections --------------------------------------------
  gemm_k<float,h16,EPI_NONE><<<dim3(256,4,1),256,0,stream>>>(
      app,0,2048, Wa16,0, ba,0, nullptr, app_proj,0, 2048, 16384,0,512);
  gemm_k<h16,h16,EPI_NONE><<<dim3(16,4,1),256,0,stream>>>(
      mot16,0,2048, Wm16,0, bm,0, nullptr, mot_proj,0, 2048, 1024,0,512);
  gemm_k<h16,h16,EPI_NONE><<<dim3(2,4,1),256,0,stream>>>(
      ques16,0,512, Wq16,0, bq,0, nullptr, q_proj,0, 512, 128,0,512);
  gemm_k<h16,h16,EPI_NONE><<<dim3(16,16,1),256,0,stream>>>(
      mot16,0,2048, Wih16,0, bih,0, bhh, xb16,0, 2048, 1024,0,2048);

  // ---- phase 2: LSTM (moved before CRN; dataflow-independent) ----------
  h16* hping[2] = {h0, h1};
  lstm_cell_k<<<dim3(256),256,0,stream>>>(xb16, nullptr, cbuf, hping[0], 0);
  for(int t=1;t<8;t++){
    gemm_k<h16,h16,EPI_NONE><<<dim3(2,16,1),256,0,stream>>>(
        hping[(t-1)&1],0,512, Whh16,0, nullptr,0, nullptr,
        hWb,0, 512, 128,0,2048);
    lstm_cell_k<<<dim3(256),256,0,stream>>>(xb16, hWb, cbuf, hping[t&1], t);
  }
  gemm_k<h16,h16,EPI_NONE><<<dim3(2,4,1),256,0,stream>>>(
      hping[1],0,512, Wvm16,0, bvm,0, nullptr, vm_proj,0, 512, 128,0,512);

  auto fill_chunk=[&](BuildArgs& a, const SelSet* ss, int z0, int nz){
    for(int s=0;s<nz;s++){ a.nsel[s]=ss[z0+s].cnt;
      for(int i=0;i<ss[z0+s].cnt;i++) a.sel[s][i]=ss[z0+s].idx[i]; }
  };

  // ---- CRN level 1 (chunks 6,6,2): objs=app_proj, cond=mot_proj --------
  cvt({W1+524288},{W1_16},{7340032});
  {
    const int z0s[3]={0,6,12}, nzs[3]={6,6,2};
    for(int ch=0;ch<3;ch++){
      const int z0=z0s[ch], nz=nzs[ch];
      BuildArgs a = {}; a.src=app_proj; a.cond=mot_proj; a.H=Hbuf;
      a.strideH=1048576; a.rdiv=1024; a.stride_hi=0; a.stride_lo=8192;
      a.obj_stride=512; a.cdiv=1; fill_chunk(a,s1,z0,nz);
      build_h_k<<<dim3(512,1,nz),256,0,stream>>>(a);
      gemm_k<h16,h16,EPI_ELU><<<dim3(16,4,nz),256,0,stream>>>(
          Hbuf,1048576,1024, W1_16+(long)z0*524288,524288,
          b1+(long)(z0+1)*512,512, nullptr,
          crnm+(long)z0*524288,524288, 1024, 1024,0,512);
    }
  }
  // ---- CRN level 2 (chunks 6,6; gated): objs=crnm, cond=q_proj ---------
  cvt({W2+524288, gW2+524288},{W2_16, gW2_16},{6291456, 6291456});
  {
    const int z0s[2]={0,6}, nzs[2]={6,6};
    for(int ch=0;ch<2;ch++){
      const int z0=z0s[ch], nz=nzs[ch];
      BuildArgs a = {}; a.src=crnm; a.cond=q_proj; a.H=Hbuf;
      a.strideH=1048576; a.rdiv=1024; a.stride_hi=0; a.stride_lo=512;
      a.obj_stride=524288; a.cdiv=8; fill_chunk(a,s2,z0,nz);
      build_h_k<<<dim3(512,1,nz),256,0,stream>>>(a);
      gemm_k<h16,h16,EPI_ELU><<<dim3(16,4,nz),256,0,stream>>>(
          Hbuf,1048576,1024, W2_16+(long)z0*524288,524288,
          b2+(long)(z0+1)*512,512, nullptr,
          crnq+(long)z0*524288,524288, 1024, 1024,0,512);
      gemm_k<h16,h16,EPI_GATE><<<dim3(16,4,nz),256,0,stream>>>(
          Hbuf,1048576,1024, gW2_16+(long)z0*524288,524288,
          gb2+(long)(z0+1)*512,512, nullptr,
          crnq+(long)z0*524288,524288, 1024, 1024,0,512);
    }
  }
  // ---- CRN level 3 (chunks 4,2): objs=crnq[t][b*8+c], cond=vm_proj -----
  cvt({W3+524288, W4+524288, gW4+524288},{W3_16, W4_16, gW4_16},
      {3145728, 2097152, 2097152});
  {
    const int z0s[2]={0,4}, nzs[2]={4,2};
    for(int ch=0;ch<2;ch++){
      const int z0=z0s[ch], nz=nzs[ch];
      BuildArgs a = {}; a.src=crnq; a.cond=vm_proj; a.H=Hbuf;
      a.strideH=1572864; a.rdiv=12; a.stride_hi=4096; a.stride_lo=524288;
      a.obj_stride=512; a.cdiv=12; fill_chunk(a,s3,z0,nz);
      build_h_k<<<dim3(768,1,nz),256,0,stream>>>(a);
      gemm_k<h16,h16,EPI_ELU><<<dim3(24,4,nz),256,0,stream>>>(
          Hbuf,1572864,1024, W3_16+(long)z0*524288,524288,
          b3+(long)(z0+1)*512,512, nullptr,
          crnvm+(long)z0*786432,786432, 1024, 1536,0,512);
    }
  }
  // ---- CRN level 4 (single chunk, gated) -> d_out (f32) ----------------
  {
    BuildArgs a = {}; a.src=crnvm; a.cond=q_proj; a.H=Hbuf;
    a.strideH=1572864; a.rdiv=1536; a.stride_hi=0; a.stride_lo=512;
    a.obj_stride=786432; a.cdiv=12; fill_chunk(a,s4,0,4);
    build_h_k<<<dim3(768,1,4),256,0,stream>>>(a);
    // out[b, s*12+t, d]: r=b*12+t -> (r/12)*24576 + (r%12)*512, +s*6144
    gemm_k<h16,float,EPI_ELU><<<dim3(24,4,4),256,0,stream>>>(
        Hbuf,1572864,1024, W4_16,524288, b4+512,512, nullptr,
        outp,6144, 1024, 12,24576,512);
    gemm_k<h16,float,EPI_GATE><<<dim3(24,4,4),256,0,stream>>>(
        Hbuf,1572864,1024, gW4_16,524288, gb4+512,512, nullptr,
        outp,6144, 1024, 12,24576,512);
  }
}